// Round 7
// baseline (463.948 us; speedup 1.0000x reference)
//
#include <hip/hip_runtime.h>
#include <stdint.h>

// Problem: B=4096, S=256, F=64, K=16, L=256
//   logits[b,k,f] = sum_s x[b,s,f] * W[f,s,k]   (x NaN->0)
//   idx[b,f] = argmax_k logits[b,k,f]           (first max wins)
//   out[b,f,l] = snippet_list[f, idx[b,f], l]
constexpr int Bn = 4096, Sn = 256, Fn = 64, Kn = 16;

// W[f][s][k] -> Wl[s][kq][f][r]  (float4 view: Wl4[(s*4+kq)*64+f])
__global__ void transpose_w_kernel(const float* __restrict__ W, float* __restrict__ Wl) {
  int t = blockIdx.x * 256 + threadIdx.x;          // t = ((s*4+kq)*64+f)*4+r
  int r = t & 3, f = (t >> 2) & 63, kq = (t >> 8) & 3, s = t >> 10;
  Wl[t] = W[(f * Sn + s) * Kn + kq * 4 + r];
}

// async global->LDS, 16B per lane; LDS dest = uniform base + lane*16
__device__ __forceinline__ void gld_lds16(const float4* g, float4* l) {
  __builtin_amdgcn_global_load_lds(
      (const __attribute__((address_space(1))) uint32_t*)g,
      (__attribute__((address_space(3))) uint32_t*)l, 16, 0, 0);
}

// GEMM+argmax. Grid 256 x 512 threads (8 waves = 4 batch-quads x 2 s-halves).
// lane=f. Wave (wb,ws): batches blk*16+wb*4+{0..3}, s in [ws*128,(ws+1)*128).
// W staged per 8-s chunk (32 KB) via global_load_lds, double-buffered per
// s-half (128 KB LDS). x register-prefetched one chunk ahead (two 32-reg
// buffers, NaN-fix applied at use). acc[4][16]=64 regs. No spill (~150 live).
__global__ __launch_bounds__(512, 2) void gemm_argmax_kernel(
    const float* __restrict__ x, const float4* __restrict__ Wl4,
    int* __restrict__ idxg) {
  __shared__ float4 Wbuf[2][2][2048];   // [ws][parity][(s8*4+kq)*64+f] 128 KB

  const int tid = threadIdx.x;
  const int lane = tid & 63;            // f
  const int w = tid >> 6;               // 0..7
  const int wb = w & 3;                 // batch-quad
  const int ws = w >> 2;                // s-half
  const int b0 = blockIdx.x * 16 + wb * 4;
  const size_t xrow = (size_t)Sn * Fn;
  const float* xb0 = x + (size_t)b0 * xrow + (size_t)(ws * 128) * Fn + lane;
  const float4* wsrc0 = Wl4 + (size_t)(ws * 128) * 256;  // 256 float4 per s-row

  float acc[4][16];
#pragma unroll
  for (int j = 0; j < 4; ++j)
#pragma unroll
    for (int k = 0; k < 16; ++k) acc[j][k] = 0.f;

  float xA[8][4], xB[8][4];

// stage W chunk c (8 s-rows = 2048 float4) into Wbuf[ws][p]; this wave's
// 8 KB slice = slices [wb*8, wb*8+8), 1 KB per global_load_lds
#define STAGEW(c, p)                                                        \
  {                                                                         \
    const float4* _src = wsrc0 + (size_t)(c) * 2048 + (wb * 8) * 64 + lane; \
    float4* _dst = &Wbuf[ws][p][(wb * 8) * 64];                             \
    _Pragma("unroll") for (int i = 0; i < 8; ++i)                           \
        gld_lds16(_src + i * 64, _dst + i * 64);                            \
  }

// load x chunk c (8 s x 4 b, coalesced 256B wave-loads) into reg buffer xn
#define LOADX(c, xn)                                                        \
  {                                                                         \
    _Pragma("unroll") for (int s8 = 0; s8 < 8; ++s8)                        \
        _Pragma("unroll") for (int j = 0; j < 4; ++j)                       \
            xn[s8][j] = xb0[(size_t)j * xrow + (size_t)((c) * 8 + s8) * Fn];\
  }

// compute chunk from Wbuf[ws][p] and reg buffer xn (NaN fix at use)
#define COMPUTE(p, xn)                                                      \
  {                                                                         \
    _Pragma("unroll") for (int s8 = 0; s8 < 8; ++s8) {                      \
      float4 wq[4];                                                         \
      _Pragma("unroll") for (int kq = 0; kq < 4; ++kq)                      \
          wq[kq] = Wbuf[ws][p][(s8 * 4 + kq) * 64 + lane];                  \
      float xv[4];                                                          \
      _Pragma("unroll") for (int j = 0; j < 4; ++j) {                       \
        float v = xn[s8][j];                                                \
        xv[j] = (v == v) ? v : 0.f;                                         \
      }                                                                     \
      float wv[16];                                                         \
      _Pragma("unroll") for (int kq = 0; kq < 4; ++kq) {                    \
        wv[4 * kq + 0] = wq[kq].x; wv[4 * kq + 1] = wq[kq].y;               \
        wv[4 * kq + 2] = wq[kq].z; wv[4 * kq + 3] = wq[kq].w;               \
      }                                                                     \
      _Pragma("unroll") for (int j = 0; j < 4; ++j)                         \
          _Pragma("unroll") for (int k = 0; k < 16; ++k)                    \
              acc[j][k] = fmaf(xv[j], wv[k], acc[j][k]);                    \
    }                                                                       \
  }

  // prologue: chunk 0 in flight, then drain
  STAGEW(0, 0);
  LOADX(0, xA);
  __syncthreads();

  for (int cc = 0; cc < 16; cc += 2) {
    // phase A: prefetch chunk cc+1, compute chunk cc (parity 0)
    STAGEW(cc + 1, 1);
    LOADX(cc + 1, xB);
    COMPUTE(0, xA);
    __syncthreads();
    // phase B: prefetch chunk cc+2, compute chunk cc+1 (parity 1)
    if (cc + 2 < 16) {
      STAGEW(cc + 2, 0);
      LOADX(cc + 2, xA);
    }
    COMPUTE(1, xB);
    __syncthreads();
  }

  // cross-s-half reduce (reuse Wbuf as 64 KB float scratch), then argmax
  float* red = (float*)&Wbuf[0][0][0];   // [(wb*4+j)*16+k][lane]
  if (ws == 1) {
#pragma unroll
    for (int j = 0; j < 4; ++j)
#pragma unroll
      for (int k = 0; k < 16; ++k)
        red[((wb * 4 + j) * 16 + k) * 64 + lane] = acc[j][k];
  }
  __syncthreads();
  if (ws == 0) {
#pragma unroll
    for (int j = 0; j < 4; ++j) {
#pragma unroll
      for (int k = 0; k < 16; ++k)
        acc[j][k] += red[((wb * 4 + j) * 16 + k) * 64 + lane];
      float bv = acc[j][0];
      int bk = 0;
#pragma unroll
      for (int k = 1; k < 16; ++k)
        if (acc[j][k] > bv) { bv = acc[j][k]; bk = k; }  // first max wins
      idxg[(b0 + j) * 64 + lane] = bk;
    }
  }
#undef STAGEW
#undef LOADX
#undef COMPUTE
}

// Pure streaming gather: row r = b*64+f (262,144 rows of 1 KB).
__global__ __launch_bounds__(256) void gather_kernel(
    const int* __restrict__ idxg, const float4* __restrict__ snip4,
    float4* __restrict__ out4) {
  const int lane = threadIdx.x & 63;
  const int gw = (blockIdx.x * 256 + threadIdx.x) >> 6;
  const int r0 = gw * 16;
  int kk[16];
#pragma unroll
  for (int i = 0; i < 16; ++i) kk[i] = idxg[r0 + i];
#pragma unroll
  for (int i = 0; i < 16; ++i) {
    const int r = r0 + i;
    const int f = r & 63;
    out4[(size_t)r * 64 + lane] = snip4[(size_t)((f * Kn + kk[i]) * 64) + lane];
  }
}

// Fallback (ws too small): R5's verified fused kernel, direct W reads.
__global__ __launch_bounds__(256, 2) void fused_fallback(
    const float* __restrict__ x, const float* __restrict__ Wsrc,
    const float4* __restrict__ snip4, float4* __restrict__ out4) {
  __shared__ int idxs[8][64];
  const int tid = threadIdx.x;
  const int lane = tid & 63;
  const int w = tid >> 6;
  const int bbase = blockIdx.x * 8;
  const int b0 = bbase + w * 2;
  const size_t xrow = (size_t)Sn * Fn;

  float acc0[16], acc1[16];
#pragma unroll
  for (int k = 0; k < 16; ++k) { acc0[k] = 0.f; acc1[k] = 0.f; }
  const float* pc0 = x + (size_t)b0 * xrow + lane;
  const float* pc1 = pc0 + xrow;
  float xc0[8], xc1[8], xn0[8], xn1[8];
#pragma unroll
  for (int j = 0; j < 8; ++j) { xn0[j] = pc0[j * 64]; xn1[j] = pc1[j * 64]; }
  for (int c = 0; c < 32; ++c) {
#pragma unroll
    for (int j = 0; j < 8; ++j) {
      float v0 = xn0[j], v1 = xn1[j];
      xc0[j] = (v0 == v0) ? v0 : 0.f;
      xc1[j] = (v1 == v1) ? v1 : 0.f;
    }
    if (c < 31) {
      pc0 += 512; pc1 += 512;
#pragma unroll
      for (int j = 0; j < 8; ++j) { xn0[j] = pc0[j * 64]; xn1[j] = pc1[j * 64]; }
    }
#pragma unroll
    for (int s8 = 0; s8 < 8; ++s8) {
      const int s = c * 8 + s8;
      float wv[16];
      const float4* wq = reinterpret_cast<const float4*>(Wsrc) + ((size_t)(lane * Sn + s) << 2);
#pragma unroll
      for (int jj = 0; jj < 4; ++jj) {
        float4 q = wq[jj];
        wv[4 * jj + 0] = q.x; wv[4 * jj + 1] = q.y; wv[4 * jj + 2] = q.z; wv[4 * jj + 3] = q.w;
      }
#pragma unroll
      for (int k = 0; k < 16; ++k) {
        acc0[k] = fmaf(xc0[s8], wv[k], acc0[k]);
        acc1[k] = fmaf(xc1[s8], wv[k], acc1[k]);
      }
    }
  }
  {
    float bv0 = acc0[0], bv1 = acc1[0];
    int bk0 = 0, bk1 = 0;
#pragma unroll
    for (int k = 1; k < 16; ++k) {
      if (acc0[k] > bv0) { bv0 = acc0[k]; bk0 = k; }
      if (acc1[k] > bv1) { bv1 = acc1[k]; bk1 = k; }
    }
    idxs[w * 2 + 0][lane] = bk0;
    idxs[w * 2 + 1][lane] = bk1;
  }
  __syncthreads();
#pragma unroll 4
  for (int it = 0; it < 128; ++it) {
    int r = (it << 2) | w;
    int bi = r >> 6, f = r & 63;
    int kk = idxs[bi][f];
    float4 v = snip4[(size_t)((f * Kn + kk) << 6) + lane];
    out4[((size_t)(bbase + bi) * Fn + f) * 64 + lane] = v;
  }
}

extern "C" void kernel_launch(void* const* d_in, const int* in_sizes, int n_in,
                              void* d_out, int out_size, void* d_ws, size_t ws_size,
                              hipStream_t stream) {
  const float* x = (const float*)d_in[0];
  const float* W = (const float*)d_in[1];
  const float* snip = (const float*)d_in[2];
  float4* out4 = (float4*)d_out;
  const float4* snip4 = (const float4*)snip;

  const size_t wl_bytes = (size_t)Sn * Fn * Kn * sizeof(float);   // 1 MB
  const size_t idx_bytes = (size_t)Bn * Fn * sizeof(int);         // 1 MB
  if (ws_size >= wl_bytes + idx_bytes) {
    float* Wl = (float*)d_ws;
    int* idxg = (int*)((char*)d_ws + wl_bytes);
    transpose_w_kernel<<<(Sn * Fn * Kn) / 256, 256, 0, stream>>>(W, Wl);
    gemm_argmax_kernel<<<Bn / 16, 512, 0, stream>>>(x, (const float4*)Wl, idxg);
    gather_kernel<<<(Bn * Fn) / (4 * 16), 256, 0, stream>>>(idxg, snip4, out4);
  } else {
    fused_fallback<<<Bn / 8, 256, 0, stream>>>(x, W, snip4, out4);
  }
}

// Round 8
// 141.645 us; speedup vs baseline: 3.2754x; 3.2754x over previous
//
#include <hip/hip_runtime.h>
#include <stdint.h>

// Problem: B=4096, S=256, F=64, K=16, L=256
//   logits[b,k,f] = sum_s x[b,s,f] * W[f,s,k]   (x NaN->0)
//   idx[b,f] = argmax_k logits[b,k,f]           (first max wins)
//   out[b,f,l] = snippet_list[f, idx[b,f], l]
constexpr int Bn = 4096, Sn = 256, Fn = 64, Kn = 16;

// W[f][s][k] -> Wl[s][kq][f][r]  (float4 view: Wl4[(s*4+kq)*64+f])
__global__ void transpose_w_kernel(const float* __restrict__ W, float* __restrict__ Wl) {
  int t = blockIdx.x * 256 + threadIdx.x;          // t = ((s*4+kq)*64+f)*4+r
  int r = t & 3, f = (t >> 2) & 63, kq = (t >> 8) & 3, s = t >> 10;
  Wl[t] = W[(f * Sn + s) * Kn + kq * 4 + r];
}

// async global->LDS, 16B per lane; LDS dest = wave-uniform base + lane*16
__device__ __forceinline__ void gld_lds16(const float4* g, float4* l) {
  __builtin_amdgcn_global_load_lds(
      (const __attribute__((address_space(1))) uint32_t*)g,
      (__attribute__((address_space(3))) uint32_t*)l, 16, 0, 0);
}

// GEMM+argmax. Grid 512 x 256 threads (4 waves). Wave w owns batches
// b0 = blk*8 + w*2 + {0,1} over FULL s (no cross-wave reduce). lane = f.
// W staged per 8-s chunk (32 KB) via global_load_lds, double-buffered
// (64 KB LDS -> 2 blocks/CU). x register-prefetched one chunk ahead
// (16 floats per buffer). Live regs ~95: acc 32 + x 32 + wq 16 + addr.
__global__ __launch_bounds__(256, 2) void gemm_argmax_kernel(
    const float* __restrict__ x, const float4* __restrict__ Wl4,
    int* __restrict__ idxg) {
  __shared__ float4 Wbuf[2][2048];   // [parity][(s8*4+kq)*64 + f]  64 KB

  const int tid = threadIdx.x;
  const int lane = tid & 63;            // f
  const int w = tid >> 6;               // 0..3
  const int b0 = blockIdx.x * 8 + w * 2;
  const size_t xrow = (size_t)Sn * Fn;
  const float* xb0 = x + (size_t)b0 * xrow + lane;

  float acc[2][16];
#pragma unroll
  for (int j = 0; j < 2; ++j)
#pragma unroll
    for (int k = 0; k < 16; ++k) acc[j][k] = 0.f;

  float xA[8][2], xB[8][2];

// stage W chunk c (8 s-rows = 2048 float4 = 32 KB) into Wbuf[p];
// wave w covers slices [w*8, w*8+8), 1024 B per gld_lds16
#define STAGEW(c, p)                                                         \
  {                                                                          \
    const float4* _src = Wl4 + (size_t)(c) * 2048 + (w * 8) * 64 + lane;     \
    float4* _dst = &Wbuf[p][(w * 8) * 64];                                   \
    _Pragma("unroll") for (int ii = 0; ii < 8; ++ii)                         \
        gld_lds16(_src + ii * 64, _dst + ii * 64);                           \
  }

// load x chunk c (8 s x 2 b, 256 B coalesced wave-loads) into reg buffer
#define LOADX(c, xn)                                                         \
  {                                                                          \
    _Pragma("unroll") for (int s8 = 0; s8 < 8; ++s8)                         \
        _Pragma("unroll") for (int j = 0; j < 2; ++j)                        \
            xn[s8][j] = xb0[(size_t)j * xrow + (size_t)((c) * 8 + s8) * Fn]; \
  }

// compute chunk from Wbuf[p] and reg buffer xn (NaN->0 applied at use)
#define COMPUTE(p, xn)                                                       \
  {                                                                          \
    _Pragma("unroll") for (int s8 = 0; s8 < 8; ++s8) {                       \
      float4 wq[4];                                                          \
      _Pragma("unroll") for (int kq = 0; kq < 4; ++kq)                       \
          wq[kq] = Wbuf[p][(s8 * 4 + kq) * 64 + lane];                       \
      float xv[2];                                                           \
      _Pragma("unroll") for (int j = 0; j < 2; ++j) {                        \
        float v = xn[s8][j];                                                 \
        xv[j] = (v == v) ? v : 0.f;                                          \
      }                                                                      \
      float wv[16];                                                          \
      _Pragma("unroll") for (int kq = 0; kq < 4; ++kq) {                     \
        wv[4 * kq + 0] = wq[kq].x; wv[4 * kq + 1] = wq[kq].y;                \
        wv[4 * kq + 2] = wq[kq].z; wv[4 * kq + 3] = wq[kq].w;                \
      }                                                                      \
      _Pragma("unroll") for (int j = 0; j < 2; ++j)                          \
          _Pragma("unroll") for (int k = 0; k < 16; ++k)                     \
              acc[j][k] = fmaf(xv[j], wv[k], acc[j][k]);                     \
    }                                                                        \
  }

  // prologue
  STAGEW(0, 0);
  LOADX(0, xA);
  __syncthreads();

  // T3-minimum 2-phase: stage next BEFORE computing current; one barrier
  // per chunk; load latency hides under ~770 cy of compute.
  for (int cc = 0; cc < 32; cc += 2) {
    // phase A: chunk cc (parity 0), prefetch cc+1 into parity 1 / xB
    STAGEW(cc + 1, 1);
    LOADX(cc + 1, xB);
    COMPUTE(0, xA);
    __syncthreads();
    // phase B: chunk cc+1 (parity 1), prefetch cc+2 into parity 0 / xA
    if (cc + 2 < 32) {
      STAGEW(cc + 2, 0);
      LOADX(cc + 2, xA);
    }
    COMPUTE(1, xB);
    __syncthreads();
  }

  // per-thread argmax (strict >, ascending k: first max wins) + idx store
#pragma unroll
  for (int j = 0; j < 2; ++j) {
    float bv = acc[j][0];
    int bk = 0;
#pragma unroll
    for (int k = 1; k < 16; ++k)
      if (acc[j][k] > bv) { bv = acc[j][k]; bk = k; }
    idxg[(b0 + j) * 64 + lane] = bk;
  }
#undef STAGEW
#undef LOADX
#undef COMPUTE
}

// Pure streaming gather: row r = b*64+f (262,144 rows of 1 KB).
__global__ __launch_bounds__(256) void gather_kernel(
    const int* __restrict__ idxg, const float4* __restrict__ snip4,
    float4* __restrict__ out4) {
  const int lane = threadIdx.x & 63;
  const int gw = (blockIdx.x * 256 + threadIdx.x) >> 6;
  const int r0 = gw * 16;
  int kk[16];
#pragma unroll
  for (int i = 0; i < 16; ++i) kk[i] = idxg[r0 + i];
#pragma unroll
  for (int i = 0; i < 16; ++i) {
    const int r = r0 + i;
    const int f = r & 63;
    out4[(size_t)r * 64 + lane] = snip4[(size_t)((f * Kn + kk[i]) * 64) + lane];
  }
}

// Fallback (ws too small): R5's verified fused kernel, direct W reads.
__global__ __launch_bounds__(256, 2) void fused_fallback(
    const float* __restrict__ x, const float* __restrict__ Wsrc,
    const float4* __restrict__ snip4, float4* __restrict__ out4) {
  __shared__ int idxs[8][64];
  const int tid = threadIdx.x;
  const int lane = tid & 63;
  const int w = tid >> 6;
  const int bbase = blockIdx.x * 8;
  const int b0 = bbase + w * 2;
  const size_t xrow = (size_t)Sn * Fn;

  float acc0[16], acc1[16];
#pragma unroll
  for (int k = 0; k < 16; ++k) { acc0[k] = 0.f; acc1[k] = 0.f; }
  const float* pc0 = x + (size_t)b0 * xrow + lane;
  const float* pc1 = pc0 + xrow;
  float xc0[8], xc1[8], xn0[8], xn1[8];
#pragma unroll
  for (int j = 0; j < 8; ++j) { xn0[j] = pc0[j * 64]; xn1[j] = pc1[j * 64]; }
  for (int c = 0; c < 32; ++c) {
#pragma unroll
    for (int j = 0; j < 8; ++j) {
      float v0 = xn0[j], v1 = xn1[j];
      xc0[j] = (v0 == v0) ? v0 : 0.f;
      xc1[j] = (v1 == v1) ? v1 : 0.f;
    }
    if (c < 31) {
      pc0 += 512; pc1 += 512;
#pragma unroll
      for (int j = 0; j < 8; ++j) { xn0[j] = pc0[j * 64]; xn1[j] = pc1[j * 64]; }
    }
#pragma unroll
    for (int s8 = 0; s8 < 8; ++s8) {
      const int s = c * 8 + s8;
      float wv[16];
      const float4* wq = reinterpret_cast<const float4*>(Wsrc) + ((size_t)(lane * Sn + s) << 2);
#pragma unroll
      for (int jj = 0; jj < 4; ++jj) {
        float4 q = wq[jj];
        wv[4 * jj + 0] = q.x; wv[4 * jj + 1] = q.y; wv[4 * jj + 2] = q.z; wv[4 * jj + 3] = q.w;
      }
#pragma unroll
      for (int k = 0; k < 16; ++k) {
        acc0[k] = fmaf(xc0[s8], wv[k], acc0[k]);
        acc1[k] = fmaf(xc1[s8], wv[k], acc1[k]);
      }
    }
  }
  {
    float bv0 = acc0[0], bv1 = acc1[0];
    int bk0 = 0, bk1 = 0;
#pragma unroll
    for (int k = 1; k < 16; ++k) {
      if (acc0[k] > bv0) { bv0 = acc0[k]; bk0 = k; }
      if (acc1[k] > bv1) { bv1 = acc1[k]; bk1 = k; }
    }
    idxs[w * 2 + 0][lane] = bk0;
    idxs[w * 2 + 1][lane] = bk1;
  }
  __syncthreads();
#pragma unroll 4
  for (int it = 0; it < 128; ++it) {
    int r = (it << 2) | w;
    int bi = r >> 6, f = r & 63;
    int kk = idxs[bi][f];
    float4 v = snip4[(size_t)((f * Kn + kk) << 6) + lane];
    out4[((size_t)(bbase + bi) * Fn + f) * 64 + lane] = v;
  }
}

extern "C" void kernel_launch(void* const* d_in, const int* in_sizes, int n_in,
                              void* d_out, int out_size, void* d_ws, size_t ws_size,
                              hipStream_t stream) {
  const float* x = (const float*)d_in[0];
  const float* W = (const float*)d_in[1];
  const float* snip = (const float*)d_in[2];
  float4* out4 = (float4*)d_out;
  const float4* snip4 = (const float4*)snip;

  const size_t wl_bytes = (size_t)Sn * Fn * Kn * sizeof(float);   // 1 MB
  const size_t idx_bytes = (size_t)Bn * Fn * sizeof(int);         // 1 MB
  if (ws_size >= wl_bytes + idx_bytes) {
    float* Wl = (float*)d_ws;
    int* idxg = (int*)((char*)d_ws + wl_bytes);
    transpose_w_kernel<<<(Sn * Fn * Kn) / 256, 256, 0, stream>>>(W, Wl);
    gemm_argmax_kernel<<<Bn / 8, 256, 0, stream>>>(x, (const float4*)Wl, idxg);
    gather_kernel<<<(Bn * Fn) / (4 * 16), 256, 0, stream>>>(idxg, snip4, out4);
  } else {
    fused_fallback<<<Bn / 8, 256, 0, stream>>>(x, W, snip4, out4);
  }
}